// Round 3
// baseline (430.337 us; speedup 1.0000x reference)
//
#include <hip/hip_runtime.h>
#include <hip/hip_cooperative_groups.h>

namespace cg = cooperative_groups;

// ---------------------------------------------------------------------------
// CrossAttention (B=1, N=4096, H=8, DH=64, DQ=320, DC=768, L=77, C=4)
// Single cooperative kernel, 5 phases + 4 grid syncs (fallback: 5 launches).
// bf16 MFMA 16x16x32 everywhere; fp32 softmax. Staging via global_load_lds
// width-16 with XOR-preswizzled global sources (linear LDS dest).
// ---------------------------------------------------------------------------

typedef __attribute__((ext_vector_type(8))) short          bf16x8;
typedef __attribute__((ext_vector_type(4))) float          f32x4;
typedef __attribute__((ext_vector_type(8))) unsigned short u16x8;

// ws byte offsets (all multiples of 16)
#define OFF_XB    0ull           // 8192*320*2      = 5,242,880
#define OFF_CTXB  5242880ull     // 9*77*768*2      = 1,064,448
#define OFF_WQT   6307328ull     // 512*320*2       =   327,680
#define OFF_WKT   6635008ull     // 512*768*2       =   786,432
#define OFF_WVT   7421440ull     // 512*768*2       =   786,432
#define OFF_WOT   8207872ull     // 320*512*2       =   327,680
#define OFF_QB    8535552ull     // 16*4096*64*2    = 8,388,608
#define OFF_KB    16924160ull    // 5*8*80*64*2     =   409,600
#define OFF_VTB   17333760ull    // 5*8*64*80*2     =   819,200
#define OFF_ATT0  18152960ull    // 4096*512*2      = 4,194,304
#define OFF_ATTC  22347264ull    // 4*4096*512*2    = 16,777,216
#define OFF_MAX   39124480ull    // 4 bytes

#define SMEM_BYTES 38400

struct Params {
  const float *x, *uc, *ck, *cv, *ex, *Wq, *Wk, *Wv, *Wo, *bo;
  const int* tp;
  unsigned short *xb, *ctxb, *WqT, *WkT, *WvT, *WoT, *qb, *kb, *vtb, *att0, *attc;
  unsigned* maxslot;
  float* out;
};

__device__ __forceinline__ unsigned short bf_cvt(float f) {
  unsigned u = __float_as_uint(f);
  unsigned r = u + 0x7FFFu + ((u >> 16) & 1u);
  return (unsigned short)(r >> 16);
}
__device__ __forceinline__ float bf2f(unsigned short u) {
  return __uint_as_float(((unsigned)u) << 16);
}
__device__ __forceinline__ unsigned enc_f(float f) {
  int b = __float_as_int(f);
  return (b >= 0) ? ((unsigned)b | 0x80000000u) : ~(unsigned)b;
}
__device__ __forceinline__ float dec_f(unsigned u) {
  unsigned b = (u & 0x80000000u) ? (u ^ 0x80000000u) : ~u;
  return __int_as_float((int)b);
}
__device__ __forceinline__ f32x4 mfma16(bf16x8 a, bf16x8 b, f32x4 c) {
  return __builtin_amdgcn_mfma_f32_16x16x32_bf16(a, b, c, 0, 0, 0);
}
__device__ __forceinline__ void gload16(const void* g, void* l) {
  __builtin_amdgcn_global_load_lds((const __attribute__((address_space(1))) void*)g,
                                   (__attribute__((address_space(3))) void*)l, 16, 0, 0);
}

__global__ void __launch_bounds__(256, 4) k_all(Params p, int plo, int phi) {
  __shared__ __align__(16) char smem[SMEM_BYTES];
  const int tid  = threadIdx.x;
  const int lane = tid & 63, w = tid >> 6;
  const int l15  = lane & 15, qd = lane >> 4;

  for (int ph = plo; ph < phi; ++ph) {
    if (ph > plo) cg::this_grid().sync();

    // ============================ P0: prep =================================
    if (ph == 0) {
      const int NVT = 4168;
      for (int v = blockIdx.x; v < NVT; v += gridDim.x) {
        if (v < 2560) {                       // x -> bf16
          size_t idx = (size_t)v * 256 + tid;
          float4 t = reinterpret_cast<const float4*>(p.x)[idx];
          ushort4 o = {bf_cvt(t.x), bf_cvt(t.y), bf_cvt(t.z), bf_cvt(t.w)};
          reinterpret_cast<ushort4*>(p.xb)[idx] = o;
          if (v == 0 && tid == 0) *p.maxslot = 0u;
        } else if (v < 3080) {                // uc/ck/cv -> bf16
          size_t r = (size_t)(v - 2560) * 256 + tid;
          if (r < 133056) {
            const float4* s = (r < 14784) ? (reinterpret_cast<const float4*>(p.uc) + r)
                            : (r < 73920) ? (reinterpret_cast<const float4*>(p.ck) + (r - 14784))
                                          : (reinterpret_cast<const float4*>(p.cv) + (r - 73920));
            float4 t = *s;
            ushort4 o = {bf_cvt(t.x), bf_cvt(t.y), bf_cvt(t.z), bf_cvt(t.w)};
            reinterpret_cast<ushort4*>(p.ctxb)[r] = o;
          }
        } else {                              // transpose-convert weights
          int q = v - 3080;
          const float* src; unsigned short* dst; int R, C, rt, ct;
          if (q < 160)      { src = p.Wq; dst = p.WqT; R = 320; C = 512; rt = q / 16; ct = q % 16; }
          else if (q < 544) { q -= 160; src = p.Wk; dst = p.WkT; R = 768; C = 512; rt = q / 16; ct = q % 16; }
          else if (q < 928) { q -= 544; src = p.Wv; dst = p.WvT; R = 768; C = 512; rt = q / 16; ct = q % 16; }
          else              { q -= 928; src = p.Wo; dst = p.WoT; R = 512; C = 320; rt = q / 10; ct = q % 10; }
          float* T = reinterpret_cast<float*>(smem);  // [32][33]
          int r0 = rt * 32, c0 = ct * 32;
          __syncthreads();
          { int r = tid >> 3, c4 = (tid & 7) * 4;
            float4 t = *reinterpret_cast<const float4*>(src + (size_t)(r0 + r) * C + c0 + c4);
            T[r * 33 + c4] = t.x; T[r * 33 + c4 + 1] = t.y;
            T[r * 33 + c4 + 2] = t.z; T[r * 33 + c4 + 3] = t.w; }
          __syncthreads();
          { int c = tid >> 3, r4 = (tid & 7) * 4;
            ushort4 o = {bf_cvt(T[r4 * 33 + c]), bf_cvt(T[(r4 + 1) * 33 + c]),
                         bf_cvt(T[(r4 + 2) * 33 + c]), bf_cvt(T[(r4 + 3) * 33 + c])};
            *reinterpret_cast<ushort4*>(dst + (size_t)(c0 + c) * R + r0 + r4) = o; }
        }
      }
    }

    // ===================== P1: q-GEMM + ctx K/V GEMMs ======================
    else if (ph == 1) {
      const int NVT = 592;
      for (int v = blockIdx.x; v < NVT; v += gridDim.x) {
        __syncthreads();
        if (v < 512) {
          // q = xb @ WqT : BM=128 BN=64 BK=32, head-split bf16 out
          int mb = (v >> 3) * 128, nb = (v & 7) * 64;
          unsigned short* As = reinterpret_cast<unsigned short*>(smem);         // [128][32]
          unsigned short* Bs = reinterpret_cast<unsigned short*>(smem + 8192);  // [64][32]
          int wr = w >> 1, wc = w & 1;
          f32x4 acc[4][2] = {};
          for (int k0 = 0; k0 < 320; k0 += 32) {
#pragma unroll
            for (int ii = 0; ii < 2; ++ii) {
              int i = w * 2 + ii;
              int r = i * 16 + (lane >> 2), cs = lane & 3;
              gload16(p.xb + (size_t)(mb + r) * 320 + k0 + ((cs ^ (r & 3)) * 8), As + i * 512);
            }
            { int r = w * 16 + (lane >> 2), cs = lane & 3;
              gload16(p.WqT + (size_t)(nb + r) * 320 + k0 + ((cs ^ (r & 3)) * 8), Bs + w * 512); }
            __syncthreads();
            bf16x8 a[4], b[2];
#pragma unroll
            for (int mi = 0; mi < 4; ++mi) {
              int row = wr * 64 + mi * 16 + l15;
              a[mi] = *reinterpret_cast<const bf16x8*>(&As[row * 32 + ((qd ^ (row & 3)) * 8)]);
            }
#pragma unroll
            for (int ni = 0; ni < 2; ++ni) {
              int row = wc * 32 + ni * 16 + l15;
              b[ni] = *reinterpret_cast<const bf16x8*>(&Bs[row * 32 + ((qd ^ (row & 3)) * 8)]);
            }
#pragma unroll
            for (int mi = 0; mi < 4; ++mi)
#pragma unroll
              for (int ni = 0; ni < 2; ++ni)
                acc[mi][ni] = mfma16(a[mi], b[ni], acc[mi][ni]);
            __syncthreads();
          }
#pragma unroll
          for (int mi = 0; mi < 4; ++mi)
#pragma unroll
            for (int ni = 0; ni < 2; ++ni)
#pragma unroll
              for (int r = 0; r < 4; ++r) {
                int m = mb + wr * 64 + mi * 16 + qd * 4 + r;
                int n = nb + wc * 32 + ni * 16 + l15;
                int b_ = m >> 12, i = m & 4095, h = n >> 6, d = n & 63;
                p.qb[((size_t)((b_ * 8 + h) * 4096 + i)) * 64 + d] = bf_cvt(acc[mi][ni][r]);
              }
        } else {
          // ctx K/V: 10 GEMMs M=77(pad80) N=512 K=768 ; BN=64 BK=64
          int u2 = v - 512;
          int g = u2 >> 3, nb = (u2 & 7) * 64;
          int kv = g >= 5, cidx = g % 5;
          int s77 = kv ? (cidx == 0 ? 0 : 4 + cidx) : (cidx == 0 ? 0 : cidx);
          const unsigned short* WT = kv ? p.WvT : p.WkT;
          unsigned short* Ac = reinterpret_cast<unsigned short*>(smem);          // [80][64]
          unsigned short* Bc = reinterpret_cast<unsigned short*>(smem + 10240);  // [64][64]
          f32x4 acc[5] = {};
          for (int k0 = 0; k0 < 768; k0 += 64) {
#pragma unroll
            for (int t = 0; t < 3; ++t) {
              int i = w + t * 4;
              if (i < 10) {
                int r = i * 8 + (lane >> 3), cs = lane & 7;
                gload16(p.ctxb + (size_t)(s77 * 77 + r) * 768 + k0 + ((cs ^ (r & 7)) * 8),
                        Ac + i * 512);
              }
            }
#pragma unroll
            for (int t = 0; t < 2; ++t) {
              int i = w * 2 + t;
              int r = i * 8 + (lane >> 3), cs = lane & 7;
              gload16(WT + (size_t)(nb + r) * 768 + k0 + ((cs ^ (r & 7)) * 8), Bc + i * 512);
            }
            __syncthreads();
#pragma unroll
            for (int ks = 0; ks < 2; ++ks) {
              int rb = w * 16 + l15;
              bf16x8 b = *reinterpret_cast<const bf16x8*>(&Bc[rb * 64 + (((ks * 4 + qd) ^ (rb & 7)) * 8)]);
#pragma unroll
              for (int mi = 0; mi < 5; ++mi) {
                int ra = mi * 16 + l15;
                bf16x8 a = *reinterpret_cast<const bf16x8*>(&Ac[ra * 64 + (((ks * 4 + qd) ^ (ra & 7)) * 8)]);
                acc[mi] = mfma16(a, b, acc[mi]);
              }
            }
            __syncthreads();
          }
#pragma unroll
          for (int mi = 0; mi < 5; ++mi)
#pragma unroll
            for (int r = 0; r < 4; ++r) {
              int j = mi * 16 + qd * 4 + r;
              int n = nb + w * 16 + l15, h = n >> 6, d = n & 63;
              unsigned short val = (j < 77) ? bf_cvt(acc[mi][r]) : (unsigned short)0;
              if (kv) p.vtb[((size_t)(cidx * 8 + h) * 64 + d) * 80 + j] = val;
              else    p.kb[((size_t)(cidx * 8 + h) * 80 + j) * 64 + d] = val;
            }
        }
      }
    }

    // ===================== P2: global max of sim_c[0] ======================
    else if (ph == 2) {
      const int NVT = 512;
      for (int v = blockIdx.x; v < NVT; v += gridDim.x) {
        __syncthreads();
        int rt = v >> 3, h = v & 7;
        int rowbase = rt * 64;
        unsigned short* Ks = reinterpret_cast<unsigned short*>(smem);  // [80][72]
        size_t kbase = (size_t)(1 * 8 + h) * 80 * 64;  // slot 1 = c0
        for (int u = tid; u < 640; u += 256) {
          int r = u >> 3, c8 = (u & 7) * 8;
          *reinterpret_cast<u16x8*>(&Ks[r * 72 + c8]) =
              *reinterpret_cast<const u16x8*>(&p.kb[kbase + (size_t)r * 64 + c8]);
        }
        __syncthreads();
        int myrow = rowbase + w * 16 + l15;
        bf16x8 aq0 = *reinterpret_cast<const bf16x8*>(&p.qb[((size_t)(8 + h) * 4096 + myrow) * 64 + qd * 8]);
        bf16x8 aq1 = *reinterpret_cast<const bf16x8*>(&p.qb[((size_t)(8 + h) * 4096 + myrow) * 64 + qd * 8 + 32]);
        float lmax = -3.4e38f;
#pragma unroll
        for (int jf = 0; jf < 5; ++jf) {
          bf16x8 b0 = *reinterpret_cast<const bf16x8*>(&Ks[(jf * 16 + l15) * 72 + qd * 8]);
          bf16x8 b1 = *reinterpret_cast<const bf16x8*>(&Ks[(jf * 16 + l15) * 72 + qd * 8 + 32]);
          f32x4 s = {};
          s = mfma16(aq0, b0, s);
          s = mfma16(aq1, b1, s);
          if (jf * 16 + l15 < 77) {
#pragma unroll
            for (int r = 0; r < 4; ++r) lmax = fmaxf(lmax, s[r] * 0.125f);
          }
        }
        for (int m = 1; m < 64; m <<= 1) lmax = fmaxf(lmax, __shfl_xor(lmax, m, 64));
        float* red = reinterpret_cast<float*>(smem + 11776);
        if (lane == 0) red[w] = lmax;
        __syncthreads();
        if (tid == 0)
          atomicMax(p.maxslot, enc_f(fmaxf(fmaxf(red[0], red[1]), fmaxf(red[2], red[3]))));
      }
    }

    // ========================= P3: fused attention =========================
    else if (ph == 3) {
      const int NVT = 2560;
      const float weight = ((float)(*p.tp)) * (4.6f / 50.0f);
      for (int v = blockIdx.x; v < NVT; v += gridDim.x) {
        __syncthreads();
        int rt = v / 40, rem = v % 40;
        int h = rem / 5, slot = rem % 5;
        int rowbase = rt * 64;
        int bh = slot ? 8 + h : h;
        unsigned short* Ks = reinterpret_cast<unsigned short*>(smem);           // [80][72]
        unsigned short* VT = reinterpret_cast<unsigned short*>(smem + 11520);   // [64][104]
        unsigned short* Ps = reinterpret_cast<unsigned short*>(smem + 24832);   // [64][104]
        for (int u = tid; u < 1024; u += 256) {  // zero pad cols 80..95
          int d = u >> 4, j = 80 + (u & 15);
          VT[d * 104 + j] = 0; Ps[d * 104 + j] = 0;
        }
        size_t kbase = (size_t)(slot * 8 + h) * 80 * 64;
        size_t vbase = (size_t)(slot * 8 + h) * 64 * 80;
        for (int u = tid; u < 640; u += 256) {
          int r = u >> 3, c8 = (u & 7) * 8;
          *reinterpret_cast<u16x8*>(&Ks[r * 72 + c8]) =
              *reinterpret_cast<const u16x8*>(&p.kb[kbase + (size_t)r * 64 + c8]);
        }
        for (int u = tid; u < 640; u += 256) {
          int d = u / 10, c8 = (u % 10) * 8;
          *reinterpret_cast<u16x8*>(&VT[d * 104 + c8]) =
              *reinterpret_cast<const u16x8*>(&p.vtb[vbase + (size_t)d * 80 + c8]);
        }
        int myrow = rowbase + w * 16 + l15;
        bf16x8 aq0 = *reinterpret_cast<const bf16x8*>(&p.qb[((size_t)bh * 4096 + myrow) * 64 + qd * 8]);
        bf16x8 aq1 = *reinterpret_cast<const bf16x8*>(&p.qb[((size_t)bh * 4096 + myrow) * 64 + qd * 8 + 32]);
        __syncthreads();
        // QK^T
        f32x4 sim[5];
#pragma unroll
        for (int jf = 0; jf < 5; ++jf) {
          bf16x8 b0 = *reinterpret_cast<const bf16x8*>(&Ks[(jf * 16 + l15) * 72 + qd * 8]);
          bf16x8 b1 = *reinterpret_cast<const bf16x8*>(&Ks[(jf * 16 + l15) * 72 + qd * 8 + 32]);
          f32x4 s = {};
          s = mfma16(aq0, b0, s);
          s = mfma16(aq1, b1, s);
          sim[jf] = s;
        }
        // softmax (|logit| small; no max-sub). slot 1 adds wmask*extra.
        float wmask_ = (slot == 1) ? weight * dec_f(*p.maxslot) : 0.f;
        int grow = rowbase + w * 16 + qd * 4;
        float rowsum[4] = {0.f, 0.f, 0.f, 0.f};
        float e[5][4];
#pragma unroll
        for (int jf = 0; jf < 5; ++jf) {
          int j = jf * 16 + l15;
#pragma unroll
          for (int r = 0; r < 4; ++r) {
            float ev = 0.f;
            if (j < 77) {
              float val = sim[jf][r] * 0.125f;
              if (slot == 1) val += wmask_ * p.ex[((size_t)h * 4096 + grow + r) * 77 + j];
              ev = __expf(val);
            }
            e[jf][r] = ev;
            rowsum[r] += ev;
          }
        }
#pragma unroll
        for (int r = 0; r < 4; ++r) {
          float s = rowsum[r];
          s += __shfl_xor(s, 1, 64); s += __shfl_xor(s, 2, 64);
          s += __shfl_xor(s, 4, 64); s += __shfl_xor(s, 8, 64);
          rowsum[r] = 1.0f / s;
        }
        // store normalized P (bf16) to wave-private rows
#pragma unroll
        for (int jf = 0; jf < 5; ++jf) {
          int j = jf * 16 + l15;
#pragma unroll
          for (int r = 0; r < 4; ++r)
            Ps[(w * 16 + qd * 4 + r) * 104 + j] = bf_cvt(e[jf][r] * rowsum[r]);
        }
        // PV
        bf16x8 pa[3];
#pragma unroll
        for (int ks = 0; ks < 3; ++ks)
          pa[ks] = *reinterpret_cast<const bf16x8*>(&Ps[(w * 16 + l15) * 104 + qd * 8 + ks * 32]);
#pragma unroll
        for (int nf = 0; nf < 4; ++nf) {
          f32x4 o = {};
#pragma unroll
          for (int ks = 0; ks < 3; ++ks) {
            bf16x8 bv = *reinterpret_cast<const bf16x8*>(&VT[(nf * 16 + l15) * 104 + qd * 8 + ks * 32]);
            o = mfma16(pa[ks], bv, o);
          }
          if (slot == 0) {
#pragma unroll
            for (int r = 0; r < 4; ++r)
              p.att0[((size_t)(grow + r)) * 512 + h * 64 + nf * 16 + l15] = bf_cvt(o[r]);
          } else {
#pragma unroll
            for (int r = 0; r < 4; ++r)
              p.attc[((size_t)((slot - 1) * 4096 + grow + r)) * 512 + h * 64 + nf * 16 + l15] = bf_cvt(o[r]);
          }
        }
      }
    }

    // ==================== P4: out = att @ Wo + bo ==========================
    else {
      const int NVT = 640;
      for (int v = blockIdx.x; v < NVT; v += gridDim.x) {
        __syncthreads();
        int mb = (v / 5) * 64, nb = (v % 5) * 64;
        bool ucpart = (mb < 4096);
        int mb2 = mb - 4096;
        unsigned short* As = reinterpret_cast<unsigned short*>(smem);          // [64][40]
        unsigned short* Bs = reinterpret_cast<unsigned short*>(smem + 5120);   // [64][32]
        f32x4 acc[4] = {};
        for (int k0 = 0; k0 < 512; k0 += 32) {
          { int r = tid >> 2, cs = tid & 3;
            u16x8 val;
            if (ucpart) {
              val = *reinterpret_cast<const u16x8*>(&p.att0[(size_t)(mb + r) * 512 + k0 + cs * 8]);
            } else {
              float f[8] = {0.f, 0.f, 0.f, 0.f, 0.f, 0.f, 0.f, 0.f};
#pragma unroll
              for (int ci = 0; ci < 4; ++ci) {
                u16x8 t = *reinterpret_cast<const u16x8*>(
                    &p.attc[((size_t)(ci * 4096 + mb2 + r)) * 512 + k0 + cs * 8]);
#pragma unroll
                for (int e2 = 0; e2 < 8; ++e2) f[e2] += bf2f((unsigned short)t[e2]);
              }
#pragma unroll
              for (int e2 = 0; e2 < 8; ++e2) val[e2] = bf_cvt(f[e2] * 0.25f);
            }
            *reinterpret_cast<u16x8*>(&As[r * 40 + cs * 8]) = val;
          }
          { int r = w * 16 + (lane >> 2), cs = lane & 3;
            gload16(p.WoT + (size_t)(nb + r) * 512 + k0 + ((cs ^ (r & 3)) * 8), Bs + w * 512); }
          __syncthreads();
          bf16x8 a = *reinterpret_cast<const bf16x8*>(&As[(w * 16 + l15) * 40 + qd * 8]);
#pragma unroll
          for (int nf = 0; nf < 4; ++nf) {
            int rb = nf * 16 + l15;
            bf16x8 b = *reinterpret_cast<const bf16x8*>(&Bs[rb * 32 + ((qd ^ (rb & 3)) * 8)]);
            acc[nf] = mfma16(a, b, acc[nf]);
          }
          __syncthreads();
        }
#pragma unroll
        for (int nf = 0; nf < 4; ++nf) {
          int n = nb + nf * 16 + l15;
          float bias = p.bo[n];
#pragma unroll
          for (int r = 0; r < 4; ++r)
            p.out[(size_t)(mb + w * 16 + qd * 4 + r) * 320 + n] = acc[nf][r] + bias;
        }
      }
    }
  }
}

extern "C" void kernel_launch(void* const* d_in, const int* in_sizes, int n_in,
                              void* d_out, int out_size, void* d_ws, size_t ws_size,
                              hipStream_t stream) {
  (void)in_sizes; (void)n_in; (void)out_size; (void)ws_size;
  char* base = (char*)d_ws;
  Params p;
  p.x  = (const float*)d_in[0];
  p.uc = (const float*)d_in[1];
  p.ck = (const float*)d_in[2];
  p.cv = (const float*)d_in[3];
  p.ex = (const float*)d_in[4];
  p.Wq = (const float*)d_in[5];
  p.Wk = (const float*)d_in[6];
  p.Wv = (const float*)d_in[7];
  p.Wo = (const float*)d_in[8];
  p.bo = (const float*)d_in[9];
  p.tp = (const int*)d_in[10];
  p.xb   = (unsigned short*)(base + OFF_XB);
  p.ctxb = (unsigned short*)(base + OFF_CTXB);
  p.WqT  = (unsigned short*)(base + OFF_WQT);
  p.WkT  = (unsigned short*)(base + OFF_WKT);
  p.WvT  = (unsigned short*)(base + OFF_WVT);
  p.WoT  = (unsigned short*)(base + OFF_WOT);
  p.qb   = (unsigned short*)(base + OFF_QB);
  p.kb   = (unsigned short*)(base + OFF_KB);
  p.vtb  = (unsigned short*)(base + OFF_VTB);
  p.att0 = (unsigned short*)(base + OFF_ATT0);
  p.attc = (unsigned short*)(base + OFF_ATTC);
  p.maxslot = (unsigned*)(base + OFF_MAX);
  p.out = (float*)d_out;

  // occupancy-derived cooperative grid (deterministic every call)
  int nb = 0;
  if (hipOccupancyMaxActiveBlocksPerMultiprocessor(&nb, (const void*)k_all, 256, 0) != hipSuccess || nb < 1)
    nb = 4;
  int ncu = 256;
  hipDeviceGetAttribute(&ncu, hipDeviceAttributeMultiprocessorCount, 0);
  int grid = nb * ncu;
  if (grid > 2560) grid = 2560;
  if (grid < 64) grid = 64;

  int plo = 0, phi = 5;
  void* args[] = {&p, &plo, &phi};
  hipError_t e = hipLaunchCooperativeKernel((void*)k_all, dim3(grid), dim3(256), args, 0, stream);
  if (e != hipSuccess) {
    (void)hipGetLastError();  // clear sticky error; fall back to 5 launches
    for (int ph = 0; ph < 5; ++ph)
      k_all<<<grid, 256, 0, stream>>>(p, ph, ph + 1);
  }
}

// Round 4
// 158.397 us; speedup vs baseline: 2.7168x; 2.7168x over previous
//
#include <hip/hip_runtime.h>

// ---------------------------------------------------------------------------
// CrossAttention (B=1, N=4096, H=8, DH=64, DQ=320, DC=768, L=77, C=4)
// 5 phase-kernels launched back-to-back on one stream (stream order = sync).
// bf16 MFMA 16x16x32; fp32 softmax. global_load_lds width-16 staging with
// XOR-preswizzled global sources (linear LDS dest).
// R3 post-mortem: cooperative grid.sync cost ~100us/sync on 8-XCD MI355X ->
// reverted to separate launches, kept the R3 phase bodies (proven correct).
// ---------------------------------------------------------------------------

typedef __attribute__((ext_vector_type(8))) short          bf16x8;
typedef __attribute__((ext_vector_type(4))) float          f32x4;
typedef __attribute__((ext_vector_type(8))) unsigned short u16x8;

// ws byte offsets (all multiples of 16)
#define OFF_XB    0ull           // 8192*320*2      = 5,242,880
#define OFF_CTXB  5242880ull     // 9*77*768*2      = 1,064,448
#define OFF_WQT   6307328ull     // 512*320*2       =   327,680
#define OFF_WKT   6635008ull     // 512*768*2       =   786,432
#define OFF_WVT   7421440ull     // 512*768*2       =   786,432
#define OFF_WOT   8207872ull     // 320*512*2       =   327,680
#define OFF_QB    8535552ull     // 16*4096*64*2    = 8,388,608
#define OFF_KB    16924160ull    // 5*8*80*64*2     =   409,600
#define OFF_VTB   17333760ull    // 5*8*64*80*2     =   819,200
#define OFF_ATT0  18152960ull    // 4096*512*2      = 4,194,304
#define OFF_ATTC  22347264ull    // 4*4096*512*2    = 16,777,216
#define OFF_MAX   39124480ull    // 4 bytes

#define SMEM_BYTES 38400

struct Params {
  const float *x, *uc, *ck, *cv, *ex, *Wq, *Wk, *Wv, *Wo, *bo;
  const int* tp;
  unsigned short *xb, *ctxb, *WqT, *WkT, *WvT, *WoT, *qb, *kb, *vtb, *att0, *attc;
  unsigned* maxslot;
  float* out;
};

__device__ __forceinline__ unsigned short bf_cvt(float f) {
  unsigned u = __float_as_uint(f);
  unsigned r = u + 0x7FFFu + ((u >> 16) & 1u);
  return (unsigned short)(r >> 16);
}
__device__ __forceinline__ float bf2f(unsigned short u) {
  return __uint_as_float(((unsigned)u) << 16);
}
__device__ __forceinline__ unsigned enc_f(float f) {
  int b = __float_as_int(f);
  return (b >= 0) ? ((unsigned)b | 0x80000000u) : ~(unsigned)b;
}
__device__ __forceinline__ float dec_f(unsigned u) {
  unsigned b = (u & 0x80000000u) ? (u ^ 0x80000000u) : ~u;
  return __int_as_float((int)b);
}
__device__ __forceinline__ f32x4 mfma16(bf16x8 a, bf16x8 b, f32x4 c) {
  return __builtin_amdgcn_mfma_f32_16x16x32_bf16(a, b, c, 0, 0, 0);
}
__device__ __forceinline__ void gload16(const void* g, void* l) {
  __builtin_amdgcn_global_load_lds((const __attribute__((address_space(1))) void*)g,
                                   (__attribute__((address_space(3))) void*)l, 16, 0, 0);
}

__global__ void __launch_bounds__(256, 4) k_all(Params p, int ph) {
  __shared__ __align__(16) char smem[SMEM_BYTES];
  const int tid  = threadIdx.x;
  const int lane = tid & 63, w = tid >> 6;
  const int l15  = lane & 15, qd = lane >> 4;
  const int v = blockIdx.x;

  // ============================ P0: prep =================================
  if (ph == 0) {
    if (v < 2560) {                       // x -> bf16
      size_t idx = (size_t)v * 256 + tid;
      float4 t = reinterpret_cast<const float4*>(p.x)[idx];
      ushort4 o = {bf_cvt(t.x), bf_cvt(t.y), bf_cvt(t.z), bf_cvt(t.w)};
      reinterpret_cast<ushort4*>(p.xb)[idx] = o;
      if (v == 0 && tid == 0) *p.maxslot = 0u;
    } else if (v < 3080) {                // uc/ck/cv -> bf16
      size_t r = (size_t)(v - 2560) * 256 + tid;
      if (r < 133056) {
        const float4* s = (r < 14784) ? (reinterpret_cast<const float4*>(p.uc) + r)
                        : (r < 73920) ? (reinterpret_cast<const float4*>(p.ck) + (r - 14784))
                                      : (reinterpret_cast<const float4*>(p.cv) + (r - 73920));
        float4 t = *s;
        ushort4 o = {bf_cvt(t.x), bf_cvt(t.y), bf_cvt(t.z), bf_cvt(t.w)};
        reinterpret_cast<ushort4*>(p.ctxb)[r] = o;
      }
    } else {                              // transpose-convert weights
      int q = v - 3080;
      const float* src; unsigned short* dst; int R, C, rt, ct;
      if (q < 160)      { src = p.Wq; dst = p.WqT; R = 320; C = 512; rt = q / 16; ct = q % 16; }
      else if (q < 544) { q -= 160; src = p.Wk; dst = p.WkT; R = 768; C = 512; rt = q / 16; ct = q % 16; }
      else if (q < 928) { q -= 544; src = p.Wv; dst = p.WvT; R = 768; C = 512; rt = q / 16; ct = q % 16; }
      else              { q -= 928; src = p.Wo; dst = p.WoT; R = 512; C = 320; rt = q / 10; ct = q % 10; }
      float* T = reinterpret_cast<float*>(smem);  // [32][33]
      int r0 = rt * 32, c0 = ct * 32;
      { int r = tid >> 3, c4 = (tid & 7) * 4;
        float4 t = *reinterpret_cast<const float4*>(src + (size_t)(r0 + r) * C + c0 + c4);
        T[r * 33 + c4] = t.x; T[r * 33 + c4 + 1] = t.y;
        T[r * 33 + c4 + 2] = t.z; T[r * 33 + c4 + 3] = t.w; }
      __syncthreads();
      { int c = tid >> 3, r4 = (tid & 7) * 4;
        ushort4 o = {bf_cvt(T[r4 * 33 + c]), bf_cvt(T[(r4 + 1) * 33 + c]),
                     bf_cvt(T[(r4 + 2) * 33 + c]), bf_cvt(T[(r4 + 3) * 33 + c])};
        *reinterpret_cast<ushort4*>(dst + (size_t)(c0 + c) * R + r0 + r4) = o; }
    }
  }

  // ===================== P1: q-GEMM + ctx K/V GEMMs ======================
  else if (ph == 1) {
    if (v < 512) {
      // q = xb @ WqT : BM=128 BN=64 BK=32, head-split bf16 out
      int mb = (v >> 3) * 128, nb = (v & 7) * 64;
      unsigned short* As = reinterpret_cast<unsigned short*>(smem);         // [128][32]
      unsigned short* Bs = reinterpret_cast<unsigned short*>(smem + 8192);  // [64][32]
      int wr = w >> 1, wc = w & 1;
      f32x4 acc[4][2] = {};
      for (int k0 = 0; k0 < 320; k0 += 32) {
#pragma unroll
        for (int ii = 0; ii < 2; ++ii) {
          int i = w * 2 + ii;
          int r = i * 16 + (lane >> 2), cs = lane & 3;
          gload16(p.xb + (size_t)(mb + r) * 320 + k0 + ((cs ^ (r & 3)) * 8), As + i * 512);
        }
        { int r = w * 16 + (lane >> 2), cs = lane & 3;
          gload16(p.WqT + (size_t)(nb + r) * 320 + k0 + ((cs ^ (r & 3)) * 8), Bs + w * 512); }
        __syncthreads();
        bf16x8 a[4], b[2];
#pragma unroll
        for (int mi = 0; mi < 4; ++mi) {
          int row = wr * 64 + mi * 16 + l15;
          a[mi] = *reinterpret_cast<const bf16x8*>(&As[row * 32 + ((qd ^ (row & 3)) * 8)]);
        }
#pragma unroll
        for (int ni = 0; ni < 2; ++ni) {
          int row = wc * 32 + ni * 16 + l15;
          b[ni] = *reinterpret_cast<const bf16x8*>(&Bs[row * 32 + ((qd ^ (row & 3)) * 8)]);
        }
#pragma unroll
        for (int mi = 0; mi < 4; ++mi)
#pragma unroll
          for (int ni = 0; ni < 2; ++ni)
            acc[mi][ni] = mfma16(a[mi], b[ni], acc[mi][ni]);
        __syncthreads();
      }
#pragma unroll
      for (int mi = 0; mi < 4; ++mi)
#pragma unroll
        for (int ni = 0; ni < 2; ++ni)
#pragma unroll
          for (int r = 0; r < 4; ++r) {
            int m = mb + wr * 64 + mi * 16 + qd * 4 + r;
            int n = nb + wc * 32 + ni * 16 + l15;
            int b_ = m >> 12, i = m & 4095, h = n >> 6, d = n & 63;
            p.qb[((size_t)((b_ * 8 + h) * 4096 + i)) * 64 + d] = bf_cvt(acc[mi][ni][r]);
          }
    } else {
      // ctx K/V: 10 GEMMs M=77(pad80) N=512 K=768 ; BN=64 BK=64
      int u2 = v - 512;
      int g = u2 >> 3, nb = (u2 & 7) * 64;
      int kv = g >= 5, cidx = g % 5;
      int s77 = kv ? (cidx == 0 ? 0 : 4 + cidx) : (cidx == 0 ? 0 : cidx);
      const unsigned short* WT = kv ? p.WvT : p.WkT;
      unsigned short* Ac = reinterpret_cast<unsigned short*>(smem);          // [80][64]
      unsigned short* Bc = reinterpret_cast<unsigned short*>(smem + 10240);  // [64][64]
      f32x4 acc[5] = {};
      for (int k0 = 0; k0 < 768; k0 += 64) {
#pragma unroll
        for (int t = 0; t < 3; ++t) {
          int i = w + t * 4;
          if (i < 10) {
            int r = i * 8 + (lane >> 3), cs = lane & 7;
            gload16(p.ctxb + (size_t)(s77 * 77 + r) * 768 + k0 + ((cs ^ (r & 7)) * 8),
                    Ac + i * 512);
          }
        }
#pragma unroll
        for (int t = 0; t < 2; ++t) {
          int i = w * 2 + t;
          int r = i * 8 + (lane >> 3), cs = lane & 7;
          gload16(WT + (size_t)(nb + r) * 768 + k0 + ((cs ^ (r & 7)) * 8), Bc + i * 512);
        }
        __syncthreads();
#pragma unroll
        for (int ks = 0; ks < 2; ++ks) {
          int rb = w * 16 + l15;
          bf16x8 b = *reinterpret_cast<const bf16x8*>(&Bc[rb * 64 + (((ks * 4 + qd) ^ (rb & 7)) * 8)]);
#pragma unroll
          for (int mi = 0; mi < 5; ++mi) {
            int ra = mi * 16 + l15;
            bf16x8 a = *reinterpret_cast<const bf16x8*>(&Ac[ra * 64 + (((ks * 4 + qd) ^ (ra & 7)) * 8)]);
            acc[mi] = mfma16(a, b, acc[mi]);
          }
        }
        __syncthreads();
      }
#pragma unroll
      for (int mi = 0; mi < 5; ++mi)
#pragma unroll
        for (int r = 0; r < 4; ++r) {
          int j = mi * 16 + qd * 4 + r;
          int n = nb + w * 16 + l15, h = n >> 6, d = n & 63;
          unsigned short val = (j < 77) ? bf_cvt(acc[mi][r]) : (unsigned short)0;
          if (kv) p.vtb[((size_t)(cidx * 8 + h) * 64 + d) * 80 + j] = val;
          else    p.kb[((size_t)(cidx * 8 + h) * 80 + j) * 64 + d] = val;
        }
    }
  }

  // ===================== P2: global max of sim_c[0] ======================
  else if (ph == 2) {
    int rt = v >> 3, h = v & 7;
    int rowbase = rt * 64;
    unsigned short* Ks = reinterpret_cast<unsigned short*>(smem);  // [80][72]
    size_t kbase = (size_t)(1 * 8 + h) * 80 * 64;  // slot 1 = c0
    for (int u = tid; u < 640; u += 256) {
      int r = u >> 3, c8 = (u & 7) * 8;
      *reinterpret_cast<u16x8*>(&Ks[r * 72 + c8]) =
          *reinterpret_cast<const u16x8*>(&p.kb[kbase + (size_t)r * 64 + c8]);
    }
    __syncthreads();
    int myrow = rowbase + w * 16 + l15;
    bf16x8 aq0 = *reinterpret_cast<const bf16x8*>(&p.qb[((size_t)(8 + h) * 4096 + myrow) * 64 + qd * 8]);
    bf16x8 aq1 = *reinterpret_cast<const bf16x8*>(&p.qb[((size_t)(8 + h) * 4096 + myrow) * 64 + qd * 8 + 32]);
    float lmax = -3.4e38f;
#pragma unroll
    for (int jf = 0; jf < 5; ++jf) {
      bf16x8 b0 = *reinterpret_cast<const bf16x8*>(&Ks[(jf * 16 + l15) * 72 + qd * 8]);
      bf16x8 b1 = *reinterpret_cast<const bf16x8*>(&Ks[(jf * 16 + l15) * 72 + qd * 8 + 32]);
      f32x4 s = {};
      s = mfma16(aq0, b0, s);
      s = mfma16(aq1, b1, s);
      if (jf * 16 + l15 < 77) {
#pragma unroll
        for (int r = 0; r < 4; ++r) lmax = fmaxf(lmax, s[r] * 0.125f);
      }
    }
    for (int m = 1; m < 64; m <<= 1) lmax = fmaxf(lmax, __shfl_xor(lmax, m, 64));
    float* red = reinterpret_cast<float*>(smem + 11776);
    if (lane == 0) red[w] = lmax;
    __syncthreads();
    if (tid == 0)
      atomicMax(p.maxslot, enc_f(fmaxf(fmaxf(red[0], red[1]), fmaxf(red[2], red[3]))));
  }

  // ========================= P3: fused attention =========================
  else if (ph == 3) {
    const float weight = ((float)(*p.tp)) * (4.6f / 50.0f);
    int rt = v / 40, rem = v % 40;
    int h = rem / 5, slot = rem % 5;
    int rowbase = rt * 64;
    int bh = slot ? 8 + h : h;
    unsigned short* Ks = reinterpret_cast<unsigned short*>(smem);           // [80][72]
    unsigned short* VT = reinterpret_cast<unsigned short*>(smem + 11520);   // [64][104]
    unsigned short* Ps = reinterpret_cast<unsigned short*>(smem + 24832);   // [64][104]
    for (int u = tid; u < 1024; u += 256) {  // zero pad cols 80..95
      int d = u >> 4, j = 80 + (u & 15);
      VT[d * 104 + j] = 0; Ps[d * 104 + j] = 0;
    }
    size_t kbase = (size_t)(slot * 8 + h) * 80 * 64;
    size_t vbase = (size_t)(slot * 8 + h) * 64 * 80;
    for (int u = tid; u < 640; u += 256) {
      int r = u >> 3, c8 = (u & 7) * 8;
      *reinterpret_cast<u16x8*>(&Ks[r * 72 + c8]) =
          *reinterpret_cast<const u16x8*>(&p.kb[kbase + (size_t)r * 64 + c8]);
    }
    for (int u = tid; u < 640; u += 256) {
      int d = u / 10, c8 = (u % 10) * 8;
      *reinterpret_cast<u16x8*>(&VT[d * 104 + c8]) =
          *reinterpret_cast<const u16x8*>(&p.vtb[vbase + (size_t)d * 80 + c8]);
    }
    int myrow = rowbase + w * 16 + l15;
    bf16x8 aq0 = *reinterpret_cast<const bf16x8*>(&p.qb[((size_t)bh * 4096 + myrow) * 64 + qd * 8]);
    bf16x8 aq1 = *reinterpret_cast<const bf16x8*>(&p.qb[((size_t)bh * 4096 + myrow) * 64 + qd * 8 + 32]);
    __syncthreads();
    // QK^T
    f32x4 sim[5];
#pragma unroll
    for (int jf = 0; jf < 5; ++jf) {
      bf16x8 b0 = *reinterpret_cast<const bf16x8*>(&Ks[(jf * 16 + l15) * 72 + qd * 8]);
      bf16x8 b1 = *reinterpret_cast<const bf16x8*>(&Ks[(jf * 16 + l15) * 72 + qd * 8 + 32]);
      f32x4 s = {};
      s = mfma16(aq0, b0, s);
      s = mfma16(aq1, b1, s);
      sim[jf] = s;
    }
    // softmax (|logit| small; no max-sub). slot 1 adds wmask*extra.
    float wmask_ = (slot == 1) ? weight * dec_f(*p.maxslot) : 0.f;
    int grow = rowbase + w * 16 + qd * 4;
    float rowsum[4] = {0.f, 0.f, 0.f, 0.f};
    float e[5][4];
#pragma unroll
    for (int jf = 0; jf < 5; ++jf) {
      int j = jf * 16 + l15;
#pragma unroll
      for (int r = 0; r < 4; ++r) {
        float ev = 0.f;
        if (j < 77) {
          float val = sim[jf][r] * 0.125f;
          if (slot == 1) val += wmask_ * p.ex[((size_t)h * 4096 + grow + r) * 77 + j];
          ev = __expf(val);
        }
        e[jf][r] = ev;
        rowsum[r] += ev;
      }
    }
#pragma unroll
    for (int r = 0; r < 4; ++r) {
      float s = rowsum[r];
      s += __shfl_xor(s, 1, 64); s += __shfl_xor(s, 2, 64);
      s += __shfl_xor(s, 4, 64); s += __shfl_xor(s, 8, 64);
      rowsum[r] = 1.0f / s;
    }
    // store normalized P (bf16) to wave-private rows
#pragma unroll
    for (int jf = 0; jf < 5; ++jf) {
      int j = jf * 16 + l15;
#pragma unroll
      for (int r = 0; r < 4; ++r)
        Ps[(w * 16 + qd * 4 + r) * 104 + j] = bf_cvt(e[jf][r] * rowsum[r]);
    }
    // PV
    bf16x8 pa[3];
#pragma unroll
    for (int ks = 0; ks < 3; ++ks)
      pa[ks] = *reinterpret_cast<const bf16x8*>(&Ps[(w * 16 + l15) * 104 + qd * 8 + ks * 32]);
#pragma unroll
    for (int nf = 0; nf < 4; ++nf) {
      f32x4 o = {};
#pragma unroll
      for (int ks = 0; ks < 3; ++ks) {
        bf16x8 bv = *reinterpret_cast<const bf16x8*>(&VT[(nf * 16 + l15) * 104 + qd * 8 + ks * 32]);
        o = mfma16(pa[ks], bv, o);
      }
      if (slot == 0) {
#pragma unroll
        for (int r = 0; r < 4; ++r)
          p.att0[((size_t)(grow + r)) * 512 + h * 64 + nf * 16 + l15] = bf_cvt(o[r]);
      } else {
#pragma unroll
        for (int r = 0; r < 4; ++r)
          p.attc[((size_t)((slot - 1) * 4096 + grow + r)) * 512 + h * 64 + nf * 16 + l15] = bf_cvt(o[r]);
      }
    }
  }

  // ==================== P4: out = att @ Wo + bo ==========================
  else {
    int mb = (v / 5) * 64, nb = (v % 5) * 64;
    bool ucpart = (mb < 4096);
    int mb2 = mb - 4096;
    unsigned short* As = reinterpret_cast<unsigned short*>(smem);          // [64][40]
    unsigned short* Bs = reinterpret_cast<unsigned short*>(smem + 5120);   // [64][32]
    f32x4 acc[4] = {};
    for (int k0 = 0; k0 < 512; k0 += 32) {
      { int r = tid >> 2, cs = tid & 3;
        u16x8 val;
        if (ucpart) {
          val = *reinterpret_cast<const u16x8*>(&p.att0[(size_t)(mb + r) * 512 + k0 + cs * 8]);
        } else {
          float f[8] = {0.f, 0.f, 0.f, 0.f, 0.f, 0.f, 0.f, 0.f};
#pragma unroll
          for (int ci = 0; ci < 4; ++ci) {
            u16x8 t = *reinterpret_cast<const u16x8*>(
                &p.attc[((size_t)(ci * 4096 + mb2 + r)) * 512 + k0 + cs * 8]);
#pragma unroll
            for (int e2 = 0; e2 < 8; ++e2) f[e2] += bf2f((unsigned short)t[e2]);
          }
#pragma unroll
          for (int e2 = 0; e2 < 8; ++e2) val[e2] = bf_cvt(f[e2] * 0.25f);
        }
        *reinterpret_cast<u16x8*>(&As[r * 40 + cs * 8]) = val;
      }
      { int r = w * 16 + (lane >> 2), cs = lane & 3;
        gload16(p.WoT + (size_t)(nb + r) * 512 + k0 + ((cs ^ (r & 3)) * 8), Bs + w * 512); }
      __syncthreads();
      bf16x8 a = *reinterpret_cast<const bf16x8*>(&As[(w * 16 + l15) * 40 + qd * 8]);
#pragma unroll
      for (int nf = 0; nf < 4; ++nf) {
        int rb = nf * 16 + l15;
        bf16x8 b = *reinterpret_cast<const bf16x8*>(&Bs[rb * 32 + ((qd ^ (rb & 3)) * 8)]);
        acc[nf] = mfma16(a, b, acc[nf]);
      }
      __syncthreads();
    }
#pragma unroll
    for (int nf = 0; nf < 4; ++nf) {
      int n = nb + nf * 16 + l15;
      float bias = p.bo[n];
#pragma unroll
      for (int r = 0; r < 4; ++r)
        p.out[(size_t)(mb + w * 16 + qd * 4 + r) * 320 + n] = acc[nf][r] + bias;
    }
  }
}

extern "C" void kernel_launch(void* const* d_in, const int* in_sizes, int n_in,
                              void* d_out, int out_size, void* d_ws, size_t ws_size,
                              hipStream_t stream) {
  (void)in_sizes; (void)n_in; (void)out_size; (void)ws_size;
  char* base = (char*)d_ws;
  Params p;
  p.x  = (const float*)d_in[0];
  p.uc = (const float*)d_in[1];
  p.ck = (const float*)d_in[2];
  p.cv = (const float*)d_in[3];
  p.ex = (const float*)d_in[4];
  p.Wq = (const float*)d_in[5];
  p.Wk = (const float*)d_in[6];
  p.Wv = (const float*)d_in[7];
  p.Wo = (const float*)d_in[8];
  p.bo = (const float*)d_in[9];
  p.tp = (const int*)d_in[10];
  p.xb   = (unsigned short*)(base + OFF_XB);
  p.ctxb = (unsigned short*)(base + OFF_CTXB);
  p.WqT  = (unsigned short*)(base + OFF_WQT);
  p.WkT  = (unsigned short*)(base + OFF_WKT);
  p.WvT  = (unsigned short*)(base + OFF_WVT);
  p.WoT  = (unsigned short*)(base + OFF_WOT);
  p.qb   = (unsigned short*)(base + OFF_QB);
  p.kb   = (unsigned short*)(base + OFF_KB);
  p.vtb  = (unsigned short*)(base + OFF_VTB);
  p.att0 = (unsigned short*)(base + OFF_ATT0);
  p.attc = (unsigned short*)(base + OFF_ATTC);
  p.maxslot = (unsigned*)(base + OFF_MAX);
  p.out = (float*)d_out;

  k_all<<<4168, 256, 0, stream>>>(p, 0);  // prep: convert + weight transpose
  k_all<<<592,  256, 0, stream>>>(p, 1);  // q-GEMM + ctx K/V GEMMs
  k_all<<<512,  256, 0, stream>>>(p, 2);  // max(sim_c0)
  k_all<<<2560, 256, 0, stream>>>(p, 3);  // fused attention (5 slots)
  k_all<<<640,  256, 0, stream>>>(p, 4);  // out-GEMM + partial merge + bias
}